// Round 6
// baseline (1113.909 us; speedup 1.0000x reference)
//
#include <hip/hip_runtime.h>
#include <hip/hip_bf16.h>
#include <stdint.h>

#define N_NODES 100000
#define N_EDGES 1000000
#define N_GRAPHS 512
#define HID 64
#define INN 32
#define INE 16

typedef unsigned int uint32;
typedef unsigned short ushort16;

__device__ __forceinline__ ushort16 f2bf(float f) {
    uint32 u = __float_as_uint(f);
    uint32 r = (u + 0x7fffu + ((u >> 16) & 1u)) >> 16;  // RNE
    return (ushort16)r;
}
__device__ __forceinline__ uint32 pack_bf2(float lo, float hi) {
    return (uint32)f2bf(lo) | ((uint32)f2bf(hi) << 16);
}
__device__ __forceinline__ float bf_lo(uint32 v) { return __uint_as_float(v << 16); }
__device__ __forceinline__ float bf_hi(uint32 v) { return __uint_as_float(v & 0xffff0000u); }

// ---------------- diag ----------------

__global__ void k_diag(float* out, float val) { out[threadIdx.x] = val; }

// ---------------- CSR build ----------------

__global__ void k_hist(const int* __restrict__ dst, int* __restrict__ counts) {
    int e = blockIdx.x * 256 + threadIdx.x;
    if (e < N_EDGES) atomicAdd(&counts[dst[e]], 1);
}

__global__ void k_scan1(const int* __restrict__ counts, int* __restrict__ bsums) {
    __shared__ int sdata[256];
    int b = blockIdx.x;
    int s = 0;
    for (int j = threadIdx.x; j < 1024; j += 256) {
        int i = b * 1024 + j;
        s += (i < N_NODES) ? counts[i] : 0;
    }
    sdata[threadIdx.x] = s; __syncthreads();
    for (int off = 128; off > 0; off >>= 1) {
        if (threadIdx.x < off) sdata[threadIdx.x] += sdata[threadIdx.x + off];
        __syncthreads();
    }
    if (threadIdx.x == 0) bsums[b] = sdata[0];
}

__global__ void k_scan2(int* __restrict__ bsums, int nb) {
    __shared__ int sh[128];
    int v = (threadIdx.x < nb) ? bsums[threadIdx.x] : 0;
    sh[threadIdx.x] = v; __syncthreads();
    for (int off = 1; off < 128; off <<= 1) {
        int t = (threadIdx.x >= off) ? sh[threadIdx.x - off] : 0;
        __syncthreads();
        sh[threadIdx.x] += t;
        __syncthreads();
    }
    if (threadIdx.x < nb) bsums[threadIdx.x] = sh[threadIdx.x] - v;  // exclusive
}

__global__ void k_scan3(const int* __restrict__ counts, const int* __restrict__ bsums,
                        int* __restrict__ rowptr, int* __restrict__ cursor) {
    __shared__ int sh[256];
    int b = blockIdx.x;
    int base = b * 1024;
    int v[4]; int s = 0;
    #pragma unroll
    for (int j = 0; j < 4; j++) {
        int i = base + threadIdx.x * 4 + j;
        v[j] = (i < N_NODES) ? counts[i] : 0;
        s += v[j];
    }
    sh[threadIdx.x] = s; __syncthreads();
    for (int off = 1; off < 256; off <<= 1) {
        int t = (threadIdx.x >= off) ? sh[threadIdx.x - off] : 0;
        __syncthreads();
        sh[threadIdx.x] += t;
        __syncthreads();
    }
    int excl = sh[threadIdx.x] - s + bsums[b];
    #pragma unroll
    for (int j = 0; j < 4; j++) {
        int i = base + threadIdx.x * 4 + j;
        if (i < N_NODES) { rowptr[i] = excl; cursor[i] = excl; excl += v[j]; }
    }
    if (b == gridDim.x - 1 && threadIdx.x == 255) rowptr[N_NODES] = excl;
}

// newpos[e] = slot of edge e in the dst-sorted order (inverse permutation)
__global__ void k_fill(const int* __restrict__ src, const int* __restrict__ dst,
                       int* __restrict__ cursor, int* __restrict__ perm_src,
                       int* __restrict__ newpos) {
    int e = blockIdx.x * 256 + threadIdx.x;
    if (e < N_EDGES) {
        int d = dst[e];
        int p = atomicAdd(&cursor[d], 1);
        perm_src[p] = src[e];
        newpos[e] = p;
    }
}

// ---------------- weight transposes (w0-type only; w1-type used naturally) ----------------

struct TransJob { const float* w; float* wt; int K; int C; };
struct TransJobs { TransJob j[6]; };

__global__ void k_transpose_all(TransJobs jobs) {
    TransJob t = jobs.j[blockIdx.x];
    int n = t.K * t.C;
    for (int i = threadIdx.x; i < n; i += 256) {
        int k = i / t.C, c = i % t.C;
        t.wt[c * t.K + k] = t.w[i];
    }
}

// ---------------- fused node-side MLP2 (lane = row, no t1 array) ----------------
// Also emits a bf16-packed copy of the output row (for next layer's gather).

template<int K0, bool RELU_RES>
__global__ __launch_bounds__(256, 2) void k_mlp(
    const float* __restrict__ in, const float* __restrict__ hprev, float* __restrict__ out,
    const float* __restrict__ w0t, const float* __restrict__ b0,
    const float* __restrict__ w1, const float* __restrict__ b1,
    uint32* __restrict__ out_bf, int nrows)
{
    int r = blockIdx.x * 256 + threadIdx.x;
    int rr = (r < nrows) ? r : (nrows - 1);
    float a[K0];
    {
        const float4* p = (const float4*)(in + (size_t)rr * K0);
        #pragma unroll
        for (int j = 0; j < K0 / 4; j++) {
            float4 v = p[j];
            a[4*j+0]=v.x; a[4*j+1]=v.y; a[4*j+2]=v.z; a[4*j+3]=v.w;
        }
    }
    float acc[HID];
    #pragma unroll
    for (int c = 0; c < HID; c++) acc[c] = b1[c];

    #pragma unroll 1
    for (int kk = 0; kk < HID / 4; kk++) {
        float t0 = b0[kk*4+0], t1v = b0[kk*4+1], t2 = b0[kk*4+2], t3 = b0[kk*4+3];
        #pragma unroll
        for (int m = 0; m < K0; m++) {
            float av = a[m];
            t0  = fmaf(av, w0t[(kk*4+0)*K0 + m], t0);
            t1v = fmaf(av, w0t[(kk*4+1)*K0 + m], t1v);
            t2  = fmaf(av, w0t[(kk*4+2)*K0 + m], t2);
            t3  = fmaf(av, w0t[(kk*4+3)*K0 + m], t3);
        }
        t0 = fmaxf(t0, 0.f); t1v = fmaxf(t1v, 0.f);
        t2 = fmaxf(t2, 0.f); t3 = fmaxf(t3, 0.f);
        const float* w1r0 = w1 + (kk*4+0) * HID;
        const float* w1r1 = w1 + (kk*4+1) * HID;
        const float* w1r2 = w1 + (kk*4+2) * HID;
        const float* w1r3 = w1 + (kk*4+3) * HID;
        #pragma unroll
        for (int c = 0; c < HID; c++) {
            float v = acc[c];
            v = fmaf(t0,  w1r0[c], v);
            v = fmaf(t1v, w1r1[c], v);
            v = fmaf(t2,  w1r2[c], v);
            v = fmaf(t3,  w1r3[c], v);
            acc[c] = v;
        }
    }

    if (RELU_RES) {
        const float4* hp = (const float4*)(hprev + (size_t)rr * HID);
        #pragma unroll
        for (int c4 = 0; c4 < HID/4; c4++) {
            float4 h4 = hp[c4];
            acc[c4*4+0] = fmaxf(acc[c4*4+0] + h4.x, 0.f);
            acc[c4*4+1] = fmaxf(acc[c4*4+1] + h4.y, 0.f);
            acc[c4*4+2] = fmaxf(acc[c4*4+2] + h4.z, 0.f);
            acc[c4*4+3] = fmaxf(acc[c4*4+3] + h4.w, 0.f);
        }
    }

    if (r < nrows) {
        float4* op = (float4*)(out + (size_t)rr * HID);
        #pragma unroll
        for (int c4 = 0; c4 < HID/4; c4++) {
            float4 res;
            res.x = acc[c4*4+0]; res.y = acc[c4*4+1];
            res.z = acc[c4*4+2]; res.w = acc[c4*4+3];
            op[c4] = res;
        }
        if (out_bf) {
            uint4* ob = (uint4*)(out_bf + (size_t)rr * 32);
            #pragma unroll
            for (int q = 0; q < 8; q++) {
                uint4 v;
                v.x = pack_bf2(acc[q*8+0], acc[q*8+1]);
                v.y = pack_bf2(acc[q*8+2], acc[q*8+3]);
                v.z = pack_bf2(acc[q*8+4], acc[q*8+5]);
                v.w = pack_bf2(acc[q*8+6], acc[q*8+7]);
                ob[q] = v;
            }
        }
    }
}

// ---------------- fused edge MLP2: natural order, scatter rows to sorted slots --------
// e_sorted stored as bf16 pairs (uint32), row = 32 uints = 128 B.
// (256,2): enough VGPRs for acc[64] to avoid AGPR ping-pong (R5: VGPR=52 => AGPR round-trips)

__global__ __launch_bounds__(256, 2) void k_edge_mlp(
    const float* __restrict__ eattr, const int* __restrict__ newpos,
    uint32* __restrict__ e_sorted,
    const float* __restrict__ w0t, const float* __restrict__ b0,
    const float* __restrict__ w1, const float* __restrict__ b1)
{
    __shared__ uint32 tile[4][64 * 33];  // per-wave 64 rows x 32 packed words, +1 pad
    int wave = threadIdx.x >> 6, lane = threadIdx.x & 63;
    int gid = blockIdx.x * 256 + threadIdx.x;
    int eid = (gid < N_EDGES) ? gid : (N_EDGES - 1);

    float a[INE];
    {
        const float4* pr = (const float4*)(eattr + (size_t)eid * INE);
        #pragma unroll
        for (int j = 0; j < INE/4; j++) {
            float4 v = pr[j];
            a[4*j+0]=v.x; a[4*j+1]=v.y; a[4*j+2]=v.z; a[4*j+3]=v.w;
        }
    }
    float acc[HID];
    #pragma unroll
    for (int c = 0; c < HID; c++) acc[c] = b1[c];

    #pragma unroll 1
    for (int kk = 0; kk < HID / 4; kk++) {
        float t0 = b0[kk*4+0], t1v = b0[kk*4+1], t2 = b0[kk*4+2], t3 = b0[kk*4+3];
        #pragma unroll
        for (int m = 0; m < INE; m++) {
            float av = a[m];
            t0  = fmaf(av, w0t[(kk*4+0)*INE + m], t0);
            t1v = fmaf(av, w0t[(kk*4+1)*INE + m], t1v);
            t2  = fmaf(av, w0t[(kk*4+2)*INE + m], t2);
            t3  = fmaf(av, w0t[(kk*4+3)*INE + m], t3);
        }
        t0 = fmaxf(t0, 0.f); t1v = fmaxf(t1v, 0.f);
        t2 = fmaxf(t2, 0.f); t3 = fmaxf(t3, 0.f);
        const float* w1r0 = w1 + (kk*4+0) * HID;
        const float* w1r1 = w1 + (kk*4+1) * HID;
        const float* w1r2 = w1 + (kk*4+2) * HID;
        const float* w1r3 = w1 + (kk*4+3) * HID;
        #pragma unroll
        for (int c = 0; c < HID; c++) {
            float v = acc[c];
            v = fmaf(t0,  w1r0[c], v);
            v = fmaf(t1v, w1r1[c], v);
            v = fmaf(t2,  w1r2[c], v);
            v = fmaf(t3,  w1r3[c], v);
            acc[c] = v;
        }
    }

    uint32* my = &tile[wave][lane * 33];
    #pragma unroll
    for (int c2 = 0; c2 < 32; c2++)
        my[c2] = pack_bf2(acc[2*c2], acc[2*c2+1]);
    __syncthreads();
    // scatter flush: each half-wave writes one 128 B row per iter (full cache lines)
    int half = lane >> 5, c = lane & 31;
    int waveBase = blockIdx.x * 256 + wave * 64;
    #pragma unroll 4
    for (int rr = 0; rr < 32; rr++) {
        int r2 = rr * 2 + half;
        int pos = waveBase + r2;
        if (pos < N_EDGES) {
            int drow = newpos[pos];
            e_sorted[(size_t)drow * 32 + c] = tile[wave][r2 * 33 + c];
        }
    }
}

// ------- GINE aggregation: z = sum relu(h[src]+e) + 1.1*h -------
// Half-wave per edge, 16-edge rounds with clamped indices: all loads of a round
// issue before any dependent use -> 2 dependent latency rounds per node.

__global__ __launch_bounds__(256, 4) void k_agg(
    const float* __restrict__ h, const uint32* __restrict__ h_bf,
    const uint32* __restrict__ e_sorted,
    const int* __restrict__ rowptr, const int* __restrict__ perm_src,
    float* __restrict__ z)
{
    int node = blockIdx.x * 4 + (threadIdx.x >> 6);
    if (node >= N_NODES) return;
    int lane = threadIdx.x & 63;
    int half = lane >> 5, c = lane & 31;   // this lane covers channels 2c, 2c+1
    int r0 = rowptr[node], r1 = rowptr[node + 1];
    const float2 hn = *(const float2*)&h[(size_t)node * HID + 2*c];  // early issue
    float accx = 0.f, accy = 0.f;
    #pragma unroll 1
    for (int base = r0; base < r1; base += 16) {
        int idxs[8]; int sidx[8];
        #pragma unroll
        for (int j = 0; j < 8; j++) {
            int idx = base + 2*j + half;
            idxs[j] = idx;
            int idxc = (idx < r1) ? idx : (r1 - 1);
            sidx[j] = perm_src[idxc];
        }
        uint32 hv[8], ev[8];
        #pragma unroll
        for (int j = 0; j < 8; j++) {
            int idxc = (idxs[j] < r1) ? idxs[j] : (r1 - 1);
            hv[j] = h_bf[(size_t)sidx[j] * 32 + c];
            ev[j] = e_sorted[(size_t)idxc * 32 + c];
        }
        #pragma unroll
        for (int j = 0; j < 8; j++) {
            float mx = fmaxf(bf_lo(hv[j]) + bf_lo(ev[j]), 0.f);
            float my = fmaxf(bf_hi(hv[j]) + bf_hi(ev[j]), 0.f);
            if (idxs[j] < r1) { accx += mx; accy += my; }
        }
    }
    accx += __shfl_xor(accx, 32);
    accy += __shfl_xor(accy, 32);
    if (half == 0) {
        float2 res;
        res.x = fmaf(1.1f, hn.x, accx);
        res.y = fmaf(1.1f, hn.y, accy);
        *(float2*)&z[(size_t)node * HID + 2*c] = res;
    }
}

// ---------------- global add pool (batch is sorted) ----------------

__global__ __launch_bounds__(256) void k_pool(
    const float* __restrict__ h, const int* __restrict__ batch, float* __restrict__ out)
{
    int g = blockIdx.x;
    int lane = threadIdx.x & 63, wave = threadIdx.x >> 6;
    int lo = 0, hi = N_NODES;
    while (lo < hi) { int mid = (lo + hi) >> 1; if (batch[mid] < g) lo = mid + 1; else hi = mid; }
    int start = lo;
    hi = N_NODES;
    while (lo < hi) { int mid = (lo + hi) >> 1; if (batch[mid] < g + 1) lo = mid + 1; else hi = mid; }
    int end = lo;
    float acc = 0.f;
    for (int n = start + wave; n < end; n += 4)
        acc += h[(size_t)n*HID + lane];
    __shared__ float sh[4][64];
    sh[wave][lane] = acc;
    __syncthreads();
    if (wave == 0)
        out[(size_t)g*HID + lane] = sh[0][lane] + sh[1][lane] + sh[2][lane] + sh[3][lane];
}

// ---------------- launch ----------------

extern "C" void kernel_launch(void* const* d_in, const int* in_sizes, int n_in,
                              void* d_out, int out_size, void* d_ws, size_t ws_size,
                              hipStream_t stream) {
    const float* x     = (const float*)d_in[0];
    const int*   eidx  = (const int*)  d_in[1];
    const float* eattr = (const float*)d_in[2];
    const int*   batch = (const int*)  d_in[3];
    const float* wn0 = (const float*)d_in[4];  const float* bn0 = (const float*)d_in[5];
    const float* wn1 = (const float*)d_in[6];  const float* bn1 = (const float*)d_in[7];
    const float* we0 = (const float*)d_in[8];  const float* be0 = (const float*)d_in[9];
    const float* we1 = (const float*)d_in[10]; const float* be1 = (const float*)d_in[11];
    const float* cw0 = (const float*)d_in[12]; const float* cb0 = (const float*)d_in[13];
    const float* cw1 = (const float*)d_in[14]; const float* cb1 = (const float*)d_in[15];
    const float* lw0 = (const float*)d_in[16]; const float* lb0 = (const float*)d_in[17];
    const float* lw1 = (const float*)d_in[18]; const float* lb1 = (const float*)d_in[19];
    const int* src = eidx;
    const int* dst = eidx + N_EDGES;

    // workspace layout (~201 MB)
    char* ws = (char*)d_ws;
    size_t off = 0;
    auto alloc = [&](size_t bytes) -> void* {
        void* p = ws + off;
        off = (off + bytes + 255) & ~(size_t)255;
        return p;
    };
    int*   counts   = (int*)  alloc((size_t)N_NODES * 4);
    int*   rowptr   = (int*)  alloc((size_t)(N_NODES + 1) * 4);
    int*   cursor   = (int*)  alloc((size_t)N_NODES * 4);
    int*   bsums    = (int*)  alloc(128 * 4);
    int*   perm_src = (int*)  alloc((size_t)N_EDGES * 4);
    int*   newpos   = (int*)  alloc((size_t)N_EDGES * 4);
    float* wt       = (float*)alloc((size_t)20480 * 4);
    float* h        = (float*)alloc((size_t)N_NODES * HID * 4);
    float* zbuf     = (float*)alloc((size_t)N_NODES * HID * 4);
    uint32* h_bf    = (uint32*)alloc((size_t)N_NODES * 32 * 4);
    uint32* e_sorted = (uint32*)alloc((size_t)N_EDGES * HID * 2);
    if (off > ws_size) {
        k_diag<<<1, 64, 0, stream>>>((float*)d_out, 1.0e9f);
        return;
    }

    // transposed w0-type weights only
    float* wn0t = wt + 0;       // 32*64 = 2048
    float* we0t = wt + 2048;    // 16*64 = 1024
    float* cw0t = wt + 3072;    // 3*4096
    float* lw0t = wt + 15360;   // 4096

    const int NB = (N_NODES + 1023) / 1024;  // 98

    hipMemsetAsync(counts, 0, (size_t)N_NODES * 4, stream);
    k_hist<<<(N_EDGES + 255) / 256, 256, 0, stream>>>(dst, counts);
    k_scan1<<<NB, 256, 0, stream>>>(counts, bsums);
    k_scan2<<<1, 128, 0, stream>>>(bsums, NB);
    k_scan3<<<NB, 256, 0, stream>>>(counts, bsums, rowptr, cursor);
    k_fill<<<(N_EDGES + 255) / 256, 256, 0, stream>>>(src, dst, cursor, perm_src, newpos);

    TransJobs jobs;
    jobs.j[0] = { wn0, wn0t, INN, HID };
    jobs.j[1] = { we0, we0t, INE, HID };
    for (int l = 0; l < 3; l++)
        jobs.j[2 + l] = { cw0 + l * 4096, cw0t + l * 4096, HID, HID };
    jobs.j[5] = { lw0, lw0t, HID, HID };
    k_transpose_all<<<6, 256, 0, stream>>>(jobs);

    const int NGRID = (N_NODES + 255) / 256;  // 391

    // node init MLP: x -> h (+ bf16 copy)
    k_mlp<INN, false><<<NGRID, 256, 0, stream>>>(x, nullptr, h, wn0t, bn0, wn1, bn1,
                                                 h_bf, N_NODES);

    // edge MLP -> e_sorted (dst-sorted order, bf16)
    k_edge_mlp<<<(N_EDGES + 255) / 256, 256, 0, stream>>>(eattr, newpos, e_sorted,
                                                          we0t, be0, we1, be1);

    const int AGRID = (N_NODES + 3) / 4;  // 25000
    for (int l = 0; l < 3; l++) {
        k_agg<<<AGRID, 256, 0, stream>>>(h, h_bf, e_sorted, rowptr, perm_src, zbuf);
        k_mlp<HID, true><<<NGRID, 256, 0, stream>>>(zbuf, h, h,
                                                    cw0t + l * 4096, cb0 + l * 64,
                                                    cw1 + l * 4096, cb1 + l * 64,
                                                    h_bf, N_NODES);
    }
    // final GINE conv (no residual/relu, no bf copy needed)
    k_agg<<<AGRID, 256, 0, stream>>>(h, h_bf, e_sorted, rowptr, perm_src, zbuf);
    k_mlp<HID, false><<<NGRID, 256, 0, stream>>>(zbuf, nullptr, h,
                                                 lw0t, lb0, lw1, lb1, nullptr, N_NODES);

    // global add pool
    k_pool<<<N_GRAPHS, 256, 0, stream>>>(h, batch, (float*)d_out);
}

// Round 8
// 963.725 us; speedup vs baseline: 1.1558x; 1.1558x over previous
//
#include <hip/hip_runtime.h>
#include <hip/hip_bf16.h>
#include <stdint.h>

#define N_NODES 100000
#define N_EDGES 1000000
#define N_GRAPHS 512
#define HID 64
#define INN 32
#define INE 16

typedef unsigned int uint32;
typedef unsigned short ushort16;
typedef __attribute__((ext_vector_type(8))) short bf8;
typedef __attribute__((ext_vector_type(4))) float f32x4;

__device__ __forceinline__ ushort16 f2bf(float f) {
    uint32 u = __float_as_uint(f);
    uint32 r = (u + 0x7fffu + ((u >> 16) & 1u)) >> 16;  // RNE
    return (ushort16)r;
}
__device__ __forceinline__ uint32 pack_bf2(float lo, float hi) {
    return (uint32)f2bf(lo) | ((uint32)f2bf(hi) << 16);
}
__device__ __forceinline__ float bf_lo(uint32 v) { return __uint_as_float(v << 16); }
__device__ __forceinline__ float bf_hi(uint32 v) { return __uint_as_float(v & 0xffff0000u); }

// ---------------- diag ----------------

__global__ void k_diag(float* out, float val) { out[threadIdx.x] = val; }

// ---------------- CSR build ----------------

__global__ void k_hist(const int* __restrict__ dst, int* __restrict__ counts) {
    int e = blockIdx.x * 256 + threadIdx.x;
    if (e < N_EDGES) atomicAdd(&counts[dst[e]], 1);
}

__global__ void k_scan1(const int* __restrict__ counts, int* __restrict__ bsums) {
    __shared__ int sdata[256];
    int b = blockIdx.x;
    int s = 0;
    for (int j = threadIdx.x; j < 1024; j += 256) {
        int i = b * 1024 + j;
        s += (i < N_NODES) ? counts[i] : 0;
    }
    sdata[threadIdx.x] = s; __syncthreads();
    for (int off = 128; off > 0; off >>= 1) {
        if (threadIdx.x < off) sdata[threadIdx.x] += sdata[threadIdx.x + off];
        __syncthreads();
    }
    if (threadIdx.x == 0) bsums[b] = sdata[0];
}

__global__ void k_scan2(int* __restrict__ bsums, int nb) {
    __shared__ int sh[128];
    int v = (threadIdx.x < nb) ? bsums[threadIdx.x] : 0;
    sh[threadIdx.x] = v; __syncthreads();
    for (int off = 1; off < 128; off <<= 1) {
        int t = (threadIdx.x >= off) ? sh[threadIdx.x - off] : 0;
        __syncthreads();
        sh[threadIdx.x] += t;
        __syncthreads();
    }
    if (threadIdx.x < nb) bsums[threadIdx.x] = sh[threadIdx.x] - v;  // exclusive
}

__global__ void k_scan3(const int* __restrict__ counts, const int* __restrict__ bsums,
                        int* __restrict__ rowptr, int* __restrict__ cursor) {
    __shared__ int sh[256];
    int b = blockIdx.x;
    int base = b * 1024;
    int v[4]; int s = 0;
    #pragma unroll
    for (int j = 0; j < 4; j++) {
        int i = base + threadIdx.x * 4 + j;
        v[j] = (i < N_NODES) ? counts[i] : 0;
        s += v[j];
    }
    sh[threadIdx.x] = s; __syncthreads();
    for (int off = 1; off < 256; off <<= 1) {
        int t = (threadIdx.x >= off) ? sh[threadIdx.x - off] : 0;
        __syncthreads();
        sh[threadIdx.x] += t;
        __syncthreads();
    }
    int excl = sh[threadIdx.x] - s + bsums[b];
    #pragma unroll
    for (int j = 0; j < 4; j++) {
        int i = base + threadIdx.x * 4 + j;
        if (i < N_NODES) { rowptr[i] = excl; cursor[i] = excl; excl += v[j]; }
    }
    if (b == gridDim.x - 1 && threadIdx.x == 255) rowptr[N_NODES] = excl;
}

// newpos[e] = slot of edge e in the dst-sorted order (inverse permutation)
__global__ void k_fill(const int* __restrict__ src, const int* __restrict__ dst,
                       int* __restrict__ cursor, int* __restrict__ perm_src,
                       int* __restrict__ newpos) {
    int e = blockIdx.x * 256 + threadIdx.x;
    if (e < N_EDGES) {
        int d = dst[e];
        int p = atomicAdd(&cursor[d], 1);
        perm_src[p] = src[e];
        newpos[e] = p;
    }
}

// ---------------- weight transposes (node-side w0 only) ----------------

struct TransJob { const float* w; float* wt; int K; int C; };
struct TransJobs { TransJob j[5]; };

__global__ void k_transpose_all(TransJobs jobs) {
    TransJob t = jobs.j[blockIdx.x];
    int n = t.K * t.C;
    for (int i = threadIdx.x; i < n; i += 256) {
        int k = i / t.C, c = i % t.C;
        t.wt[c * t.K + k] = t.w[i];
    }
}

// ---------------- fused node-side MLP2 (lane = row) ----------------

template<int K0, bool RELU_RES>
__global__ __launch_bounds__(256, 2) void k_mlp(
    const float* __restrict__ in, const float* __restrict__ hprev, float* __restrict__ out,
    const float* __restrict__ w0t, const float* __restrict__ b0,
    const float* __restrict__ w1, const float* __restrict__ b1,
    uint32* __restrict__ out_bf, int nrows)
{
    int r = blockIdx.x * 256 + threadIdx.x;
    int rr = (r < nrows) ? r : (nrows - 1);
    float a[K0];
    {
        const float4* p = (const float4*)(in + (size_t)rr * K0);
        #pragma unroll
        for (int j = 0; j < K0 / 4; j++) {
            float4 v = p[j];
            a[4*j+0]=v.x; a[4*j+1]=v.y; a[4*j+2]=v.z; a[4*j+3]=v.w;
        }
    }
    float acc[HID];
    #pragma unroll
    for (int c = 0; c < HID; c++) acc[c] = b1[c];

    #pragma unroll 1
    for (int kk = 0; kk < HID / 4; kk++) {
        float t0 = b0[kk*4+0], t1v = b0[kk*4+1], t2 = b0[kk*4+2], t3 = b0[kk*4+3];
        #pragma unroll
        for (int m = 0; m < K0; m++) {
            float av = a[m];
            t0  = fmaf(av, w0t[(kk*4+0)*K0 + m], t0);
            t1v = fmaf(av, w0t[(kk*4+1)*K0 + m], t1v);
            t2  = fmaf(av, w0t[(kk*4+2)*K0 + m], t2);
            t3  = fmaf(av, w0t[(kk*4+3)*K0 + m], t3);
        }
        t0 = fmaxf(t0, 0.f); t1v = fmaxf(t1v, 0.f);
        t2 = fmaxf(t2, 0.f); t3 = fmaxf(t3, 0.f);
        const float* w1r0 = w1 + (kk*4+0) * HID;
        const float* w1r1 = w1 + (kk*4+1) * HID;
        const float* w1r2 = w1 + (kk*4+2) * HID;
        const float* w1r3 = w1 + (kk*4+3) * HID;
        #pragma unroll
        for (int c = 0; c < HID; c++) {
            float v = acc[c];
            v = fmaf(t0,  w1r0[c], v);
            v = fmaf(t1v, w1r1[c], v);
            v = fmaf(t2,  w1r2[c], v);
            v = fmaf(t3,  w1r3[c], v);
            acc[c] = v;
        }
    }

    if (RELU_RES) {
        const float4* hp = (const float4*)(hprev + (size_t)rr * HID);
        #pragma unroll
        for (int c4 = 0; c4 < HID/4; c4++) {
            float4 h4 = hp[c4];
            acc[c4*4+0] = fmaxf(acc[c4*4+0] + h4.x, 0.f);
            acc[c4*4+1] = fmaxf(acc[c4*4+1] + h4.y, 0.f);
            acc[c4*4+2] = fmaxf(acc[c4*4+2] + h4.z, 0.f);
            acc[c4*4+3] = fmaxf(acc[c4*4+3] + h4.w, 0.f);
        }
    }

    if (r < nrows) {
        float4* op = (float4*)(out + (size_t)rr * HID);
        #pragma unroll
        for (int c4 = 0; c4 < HID/4; c4++) {
            float4 res;
            res.x = acc[c4*4+0]; res.y = acc[c4*4+1];
            res.z = acc[c4*4+2]; res.w = acc[c4*4+3];
            op[c4] = res;
        }
        if (out_bf) {
            uint4* ob = (uint4*)(out_bf + (size_t)rr * 32);
            #pragma unroll
            for (int q = 0; q < 8; q++) {
                uint4 v;
                v.x = pack_bf2(acc[q*8+0], acc[q*8+1]);
                v.y = pack_bf2(acc[q*8+2], acc[q*8+3]);
                v.z = pack_bf2(acc[q*8+4], acc[q*8+5]);
                v.w = pack_bf2(acc[q*8+6], acc[q*8+7]);
                ob[q] = v;
            }
        }
    }
}

// ---------------- edge MLP2 via MFMA ----------------
// Per wave: 16 edges. L1: [16x16(pad32)] @ [16x64] via 4x mfma_16x16x32_bf16.
// C1 (+b0, relu) -> per-wave LDS tile -> A2 frags -> L2: 4 col-tiles x 2 MFMA (K=64).
// Epilogue: +b1 -> bf16 LDS tile -> half-wave per row scatter to dst-sorted slot.
// ALL LDS accesses are ushort or short8 (legal aliasing); uint32 packing is in-register.
// __syncthreads() pins compiler ordering at each phase boundary (uniform loop count).

__global__ __launch_bounds__(256, 4) void k_edge_mlp_mfma(
    const float* __restrict__ eattr, const int* __restrict__ newpos,
    uint32* __restrict__ e_sorted,
    const float* __restrict__ w0, const float* __restrict__ b0,
    const float* __restrict__ w1, const float* __restrict__ b1)
{
    __shared__ ushort tile[4][16 * 72];  // per-wave 16 rows x 64 bf16 (+8 pad)
    const int wave = threadIdx.x >> 6, lane = threadIdx.x & 63;
    const int quad = lane >> 4, mn = lane & 15;
    ushort* T = &tile[wave][0];

    // ---- weight fragments (loaded once per block, reused over chunks) ----
    bf8 w0f[4];  // layer1 B-frags, col-tile t: B[k=quad*8+j][n=t*16+mn]
    #pragma unroll
    for (int t = 0; t < 4; t++) {
        #pragma unroll
        for (int j = 0; j < 8; j++) {
            int k = quad * 8 + j;
            float v = (k < INE) ? w0[k * HID + t * 16 + mn] : 0.f;
            w0f[t][j] = (short)f2bf(v);
        }
    }
    bf8 w1f[4][2];  // layer2 B-frags, col-tile t, k-frag f
    #pragma unroll
    for (int t = 0; t < 4; t++)
        #pragma unroll
        for (int f = 0; f < 2; f++)
            #pragma unroll
            for (int j = 0; j < 8; j++) {
                int k = f * 32 + quad * 8 + j;
                w1f[t][f][j] = (short)f2bf(w1[k * HID + t * 16 + mn]);
            }
    float b0v[4], b1v[4];
    #pragma unroll
    for (int t = 0; t < 4; t++) { b0v[t] = b0[t*16+mn]; b1v[t] = b1[t*16+mn]; }

    const int nChunks = N_EDGES / 64;  // 15625 (exact)
    for (int chunk = blockIdx.x; chunk < nChunks; chunk += gridDim.x) {
        const int ebase = chunk * 64 + wave * 16;  // this wave's 16 edges
        // A1 frag: eattr[ebase+mn][quad*8+j], zero for quad>=2 (K pad 16->32)
        bf8 a1 = {};
        if (quad < 2) {
            const float4* pr = (const float4*)(eattr + (size_t)(ebase + mn) * INE + quad * 8);
            float4 v0 = pr[0], v1 = pr[1];
            a1[0]=(short)f2bf(v0.x); a1[1]=(short)f2bf(v0.y);
            a1[2]=(short)f2bf(v0.z); a1[3]=(short)f2bf(v0.w);
            a1[4]=(short)f2bf(v1.x); a1[5]=(short)f2bf(v1.y);
            a1[6]=(short)f2bf(v1.z); a1[7]=(short)f2bf(v1.w);
        }
        // layer1: 4 col-tiles -> LDS (bf16, A-ready layout)
        #pragma unroll
        for (int t = 0; t < 4; t++) {
            f32x4 c = {0.f, 0.f, 0.f, 0.f};
            c = __builtin_amdgcn_mfma_f32_16x16x32_bf16(a1, w0f[t], c, 0, 0, 0);
            #pragma unroll
            for (int rg = 0; rg < 4; rg++) {
                int row = quad * 4 + rg;
                T[row * 72 + t * 16 + mn] = f2bf(fmaxf(c[rg] + b0v[t], 0.f));
            }
        }
        __syncthreads();  // L1 writes visible+ordered before A2 reads
        // A2 frags from LDS: A[m=mn][k=f*32+quad*8+j]
        bf8 a2[2];
        #pragma unroll
        for (int f = 0; f < 2; f++)
            a2[f] = *(const bf8*)&T[mn * 72 + f * 32 + quad * 8];
        // layer2: 4 col-tiles, K=64 via 2 chained MFMAs; epilogue back to LDS
        #pragma unroll
        for (int t = 0; t < 4; t++) {
            f32x4 c = {0.f, 0.f, 0.f, 0.f};
            c = __builtin_amdgcn_mfma_f32_16x16x32_bf16(a2[0], w1f[t][0], c, 0, 0, 0);
            c = __builtin_amdgcn_mfma_f32_16x16x32_bf16(a2[1], w1f[t][1], c, 0, 0, 0);
            #pragma unroll
            for (int rg = 0; rg < 4; rg++) {
                int row = quad * 4 + rg;
                T[row * 72 + t * 16 + mn] = f2bf(c[rg] + b1v[t]);
            }
        }
        __syncthreads();  // L2 writes ordered before flush reads
        // flush: half-wave per row, pack uint32 IN-REGISTER (no type punning on LDS)
        int half = lane >> 5, c32 = lane & 31;
        #pragma unroll
        for (int rr = 0; rr < 8; rr++) {
            int row = rr * 2 + half;
            int drow = newpos[ebase + row];
            uint32 lo = T[row * 72 + c32 * 2];
            uint32 hi = T[row * 72 + c32 * 2 + 1];
            e_sorted[(size_t)drow * 32 + c32] = lo | (hi << 16);
        }
        __syncthreads();  // flush reads complete before next chunk overwrites tile
    }
}

// ------- GINE aggregation: z = sum relu(h[src]+e) + 1.1*h -------

__global__ __launch_bounds__(256, 4) void k_agg(
    const float* __restrict__ h, const uint32* __restrict__ h_bf,
    const uint32* __restrict__ e_sorted,
    const int* __restrict__ rowptr, const int* __restrict__ perm_src,
    float* __restrict__ z)
{
    int node = blockIdx.x * 4 + (threadIdx.x >> 6);
    if (node >= N_NODES) return;
    int lane = threadIdx.x & 63;
    int half = lane >> 5, c = lane & 31;   // this lane covers channels 2c, 2c+1
    int r0 = rowptr[node], r1 = rowptr[node + 1];
    const float2 hn = *(const float2*)&h[(size_t)node * HID + 2*c];  // early issue
    float accx = 0.f, accy = 0.f;
    #pragma unroll 1
    for (int base = r0; base < r1; base += 16) {
        int idxs[8]; int sidx[8];
        #pragma unroll
        for (int j = 0; j < 8; j++) {
            int idx = base + 2*j + half;
            idxs[j] = idx;
            int idxc = (idx < r1) ? idx : (r1 - 1);
            sidx[j] = perm_src[idxc];
        }
        uint32 hv[8], ev[8];
        #pragma unroll
        for (int j = 0; j < 8; j++) {
            int idxc = (idxs[j] < r1) ? idxs[j] : (r1 - 1);
            hv[j] = h_bf[(size_t)sidx[j] * 32 + c];
            ev[j] = e_sorted[(size_t)idxc * 32 + c];
        }
        #pragma unroll
        for (int j = 0; j < 8; j++) {
            float mx = fmaxf(bf_lo(hv[j]) + bf_lo(ev[j]), 0.f);
            float my = fmaxf(bf_hi(hv[j]) + bf_hi(ev[j]), 0.f);
            if (idxs[j] < r1) { accx += mx; accy += my; }
        }
    }
    accx += __shfl_xor(accx, 32);
    accy += __shfl_xor(accy, 32);
    if (half == 0) {
        float2 res;
        res.x = fmaf(1.1f, hn.x, accx);
        res.y = fmaf(1.1f, hn.y, accy);
        *(float2*)&z[(size_t)node * HID + 2*c] = res;
    }
}

// ---------------- global add pool (batch is sorted) ----------------

__global__ __launch_bounds__(256) void k_pool(
    const float* __restrict__ h, const int* __restrict__ batch, float* __restrict__ out)
{
    int g = blockIdx.x;
    int lane = threadIdx.x & 63, wave = threadIdx.x >> 6;
    int lo = 0, hi = N_NODES;
    while (lo < hi) { int mid = (lo + hi) >> 1; if (batch[mid] < g) lo = mid + 1; else hi = mid; }
    int start = lo;
    hi = N_NODES;
    while (lo < hi) { int mid = (lo + hi) >> 1; if (batch[mid] < g + 1) lo = mid + 1; else hi = mid; }
    int end = lo;
    float acc = 0.f;
    for (int n = start + wave; n < end; n += 4)
        acc += h[(size_t)n*HID + lane];
    __shared__ float sh[4][64];
    sh[wave][lane] = acc;
    __syncthreads();
    if (wave == 0)
        out[(size_t)g*HID + lane] = sh[0][lane] + sh[1][lane] + sh[2][lane] + sh[3][lane];
}

// ---------------- launch ----------------

extern "C" void kernel_launch(void* const* d_in, const int* in_sizes, int n_in,
                              void* d_out, int out_size, void* d_ws, size_t ws_size,
                              hipStream_t stream) {
    const float* x     = (const float*)d_in[0];
    const int*   eidx  = (const int*)  d_in[1];
    const float* eattr = (const float*)d_in[2];
    const int*   batch = (const int*)  d_in[3];
    const float* wn0 = (const float*)d_in[4];  const float* bn0 = (const float*)d_in[5];
    const float* wn1 = (const float*)d_in[6];  const float* bn1 = (const float*)d_in[7];
    const float* we0 = (const float*)d_in[8];  const float* be0 = (const float*)d_in[9];
    const float* we1 = (const float*)d_in[10]; const float* be1 = (const float*)d_in[11];
    const float* cw0 = (const float*)d_in[12]; const float* cb0 = (const float*)d_in[13];
    const float* cw1 = (const float*)d_in[14]; const float* cb1 = (const float*)d_in[15];
    const float* lw0 = (const float*)d_in[16]; const float* lb0 = (const float*)d_in[17];
    const float* lw1 = (const float*)d_in[18]; const float* lb1 = (const float*)d_in[19];
    const int* src = eidx;
    const int* dst = eidx + N_EDGES;

    // workspace layout (~201 MB)
    char* ws = (char*)d_ws;
    size_t off = 0;
    auto alloc = [&](size_t bytes) -> void* {
        void* p = ws + off;
        off = (off + bytes + 255) & ~(size_t)255;
        return p;
    };
    int*   counts   = (int*)  alloc((size_t)N_NODES * 4);
    int*   rowptr   = (int*)  alloc((size_t)(N_NODES + 1) * 4);
    int*   cursor   = (int*)  alloc((size_t)N_NODES * 4);
    int*   bsums    = (int*)  alloc(128 * 4);
    int*   perm_src = (int*)  alloc((size_t)N_EDGES * 4);
    int*   newpos   = (int*)  alloc((size_t)N_EDGES * 4);
    float* wt       = (float*)alloc((size_t)18432 * 4);
    float* h        = (float*)alloc((size_t)N_NODES * HID * 4);
    float* zbuf     = (float*)alloc((size_t)N_NODES * HID * 4);
    uint32* h_bf    = (uint32*)alloc((size_t)N_NODES * 32 * 4);
    uint32* e_sorted = (uint32*)alloc((size_t)N_EDGES * HID * 2);
    if (off > ws_size) {
        k_diag<<<1, 64, 0, stream>>>((float*)d_out, 1.0e9f);
        return;
    }

    // transposed node-side w0 weights
    float* wn0t = wt + 0;       // 32*64 = 2048
    float* cw0t = wt + 2048;    // 3*4096
    float* lw0t = wt + 14336;   // 4096

    const int NB = (N_NODES + 1023) / 1024;  // 98

    hipMemsetAsync(counts, 0, (size_t)N_NODES * 4, stream);
    k_hist<<<(N_EDGES + 255) / 256, 256, 0, stream>>>(dst, counts);
    k_scan1<<<NB, 256, 0, stream>>>(counts, bsums);
    k_scan2<<<1, 128, 0, stream>>>(bsums, NB);
    k_scan3<<<NB, 256, 0, stream>>>(counts, bsums, rowptr, cursor);
    k_fill<<<(N_EDGES + 255) / 256, 256, 0, stream>>>(src, dst, cursor, perm_src, newpos);

    TransJobs jobs;
    jobs.j[0] = { wn0, wn0t, INN, HID };
    for (int l = 0; l < 3; l++)
        jobs.j[1 + l] = { cw0 + l * 4096, cw0t + l * 4096, HID, HID };
    jobs.j[4] = { lw0, lw0t, HID, HID };
    k_transpose_all<<<5, 256, 0, stream>>>(jobs);

    const int NGRID = (N_NODES + 255) / 256;  // 391

    // node init MLP: x -> h (+ bf16 copy)
    k_mlp<INN, false><<<NGRID, 256, 0, stream>>>(x, nullptr, h, wn0t, bn0, wn1, bn1,
                                                 h_bf, N_NODES);

    // edge MLP via MFMA -> e_sorted (dst-sorted order, bf16)
    k_edge_mlp_mfma<<<1024, 256, 0, stream>>>(eattr, newpos, e_sorted,
                                              we0, be0, we1, be1);

    const int AGRID = (N_NODES + 3) / 4;  // 25000
    for (int l = 0; l < 3; l++) {
        k_agg<<<AGRID, 256, 0, stream>>>(h, h_bf, e_sorted, rowptr, perm_src, zbuf);
        k_mlp<HID, true><<<NGRID, 256, 0, stream>>>(zbuf, h, h,
                                                    cw0t + l * 4096, cb0 + l * 64,
                                                    cw1 + l * 4096, cb1 + l * 64,
                                                    h_bf, N_NODES);
    }
    // final GINE conv (no residual/relu, no bf copy needed)
    k_agg<<<AGRID, 256, 0, stream>>>(h, h_bf, e_sorted, rowptr, perm_src, zbuf);
    k_mlp<HID, false><<<NGRID, 256, 0, stream>>>(zbuf, nullptr, h,
                                                 lw0t, lb0, lw1, lb1, nullptr, N_NODES);

    // global add pool
    k_pool<<<N_GRAPHS, 256, 0, stream>>>(h, batch, (float*)d_out);
}

// Round 9
// 607.745 us; speedup vs baseline: 1.8329x; 1.5857x over previous
//
#include <hip/hip_runtime.h>
#include <hip/hip_bf16.h>
#include <stdint.h>

#define N_NODES 100000
#define N_EDGES 1000000
#define N_GRAPHS 512
#define HID 64
#define INN 32
#define INE 16

typedef unsigned int uint32;
typedef unsigned short ushort16;
typedef __attribute__((ext_vector_type(8))) short bf8;
typedef __attribute__((ext_vector_type(4))) float f32x4;

__device__ __forceinline__ ushort16 f2bf(float f) {
    uint32 u = __float_as_uint(f);
    uint32 r = (u + 0x7fffu + ((u >> 16) & 1u)) >> 16;  // RNE
    return (ushort16)r;
}
__device__ __forceinline__ uint32 pack_bf2(float lo, float hi) {
    return (uint32)f2bf(lo) | ((uint32)f2bf(hi) << 16);
}
__device__ __forceinline__ float bf_lo(uint32 v) { return __uint_as_float(v << 16); }
__device__ __forceinline__ float bf_hi(uint32 v) { return __uint_as_float(v & 0xffff0000u); }

// ---------------- diag ----------------

__global__ void k_diag(float* out, float val) { out[threadIdx.x] = val; }

// ---------------- CSR build ----------------

__global__ void k_hist(const int* __restrict__ dst, int* __restrict__ counts) {
    int e = blockIdx.x * 256 + threadIdx.x;
    if (e < N_EDGES) atomicAdd(&counts[dst[e]], 1);
}

__global__ void k_scan1(const int* __restrict__ counts, int* __restrict__ bsums) {
    __shared__ int sdata[256];
    int b = blockIdx.x;
    int s = 0;
    for (int j = threadIdx.x; j < 1024; j += 256) {
        int i = b * 1024 + j;
        s += (i < N_NODES) ? counts[i] : 0;
    }
    sdata[threadIdx.x] = s; __syncthreads();
    for (int off = 128; off > 0; off >>= 1) {
        if (threadIdx.x < off) sdata[threadIdx.x] += sdata[threadIdx.x + off];
        __syncthreads();
    }
    if (threadIdx.x == 0) bsums[b] = sdata[0];
}

__global__ void k_scan2(int* __restrict__ bsums, int nb) {
    __shared__ int sh[128];
    int v = (threadIdx.x < nb) ? bsums[threadIdx.x] : 0;
    sh[threadIdx.x] = v; __syncthreads();
    for (int off = 1; off < 128; off <<= 1) {
        int t = (threadIdx.x >= off) ? sh[threadIdx.x - off] : 0;
        __syncthreads();
        sh[threadIdx.x] += t;
        __syncthreads();
    }
    if (threadIdx.x < nb) bsums[threadIdx.x] = sh[threadIdx.x] - v;  // exclusive
}

__global__ void k_scan3(const int* __restrict__ counts, const int* __restrict__ bsums,
                        int* __restrict__ rowptr, int* __restrict__ cursor) {
    __shared__ int sh[256];
    int b = blockIdx.x;
    int base = b * 1024;
    int v[4]; int s = 0;
    #pragma unroll
    for (int j = 0; j < 4; j++) {
        int i = base + threadIdx.x * 4 + j;
        v[j] = (i < N_NODES) ? counts[i] : 0;
        s += v[j];
    }
    sh[threadIdx.x] = s; __syncthreads();
    for (int off = 1; off < 256; off <<= 1) {
        int t = (threadIdx.x >= off) ? sh[threadIdx.x - off] : 0;
        __syncthreads();
        sh[threadIdx.x] += t;
        __syncthreads();
    }
    int excl = sh[threadIdx.x] - s + bsums[b];
    #pragma unroll
    for (int j = 0; j < 4; j++) {
        int i = base + threadIdx.x * 4 + j;
        if (i < N_NODES) { rowptr[i] = excl; cursor[i] = excl; excl += v[j]; }
    }
    if (b == gridDim.x - 1 && threadIdx.x == 255) rowptr[N_NODES] = excl;
}

// newpos[e] = slot of edge e in the dst-sorted order (inverse permutation)
__global__ void k_fill(const int* __restrict__ src, const int* __restrict__ dst,
                       int* __restrict__ cursor, int* __restrict__ perm_src,
                       int* __restrict__ newpos) {
    int e = blockIdx.x * 256 + threadIdx.x;
    if (e < N_EDGES) {
        int d = dst[e];
        int p = atomicAdd(&cursor[d], 1);
        perm_src[p] = src[e];
        newpos[e] = p;
    }
}

// ---------------- node-side MLP2 via MFMA ----------------
// Per wave: 16 rows. L1: [16xK0] @ [K0x64] via NF chained mfma_16x16x32_bf16 per col-tile.
// C1 (+b0, relu) -> per-wave LDS tile -> A2 frags -> L2: 4 col-tiles x 2 MFMA (K=64).
// Epilogue: +b1, optional (residual + relu); write f32 out directly from C regs and
// bf16 out_bf via LDS tile (128 B rows). Natural-order rows, no scatter.
// Fragment layouts identical to k_edge_mlp_mfma (verified R8).

template<int K0, bool RELU_RES>
__global__ __launch_bounds__(256, 3) void k_mlp_mfma(
    const float* __restrict__ in, const float* __restrict__ hprev, float* __restrict__ out,
    const float* __restrict__ w0, const float* __restrict__ b0,
    const float* __restrict__ w1, const float* __restrict__ b1,
    uint32* __restrict__ out_bf, int nrows)
{
    constexpr int NF = K0 / 32;  // K-frags for layer 1
    __shared__ ushort tile[4][16 * 72];
    const int wave = threadIdx.x >> 6, lane = threadIdx.x & 63;
    const int quad = lane >> 4, mn = lane & 15;
    ushort* T = &tile[wave][0];

    // ---- weight fragments: B[k][n=t*16+mn], k = f*32 + quad*8 + j ----
    bf8 w0f[4][NF];
    #pragma unroll
    for (int t = 0; t < 4; t++)
        #pragma unroll
        for (int f = 0; f < NF; f++)
            #pragma unroll
            for (int j = 0; j < 8; j++) {
                int k = f * 32 + quad * 8 + j;
                w0f[t][f][j] = (short)f2bf(w0[k * HID + t * 16 + mn]);
            }
    bf8 w1f[4][2];
    #pragma unroll
    for (int t = 0; t < 4; t++)
        #pragma unroll
        for (int f = 0; f < 2; f++)
            #pragma unroll
            for (int j = 0; j < 8; j++) {
                int k = f * 32 + quad * 8 + j;
                w1f[t][f][j] = (short)f2bf(w1[k * HID + t * 16 + mn]);
            }
    float b0v[4], b1v[4];
    #pragma unroll
    for (int t = 0; t < 4; t++) { b0v[t] = b0[t*16+mn]; b1v[t] = b1[t*16+mn]; }

    const int ebase = blockIdx.x * 64 + wave * 16;  // this wave's 16 rows
    // A1 frags: in[rowA][f*32 + quad*8 + j], rowA clamped
    int rowA = ebase + mn; if (rowA > nrows - 1) rowA = nrows - 1;
    bf8 a1[NF];
    #pragma unroll
    for (int f = 0; f < NF; f++) {
        const float4* pr = (const float4*)(in + (size_t)rowA * K0 + f * 32 + quad * 8);
        float4 v0 = pr[0], v1 = pr[1];
        a1[f][0]=(short)f2bf(v0.x); a1[f][1]=(short)f2bf(v0.y);
        a1[f][2]=(short)f2bf(v0.z); a1[f][3]=(short)f2bf(v0.w);
        a1[f][4]=(short)f2bf(v1.x); a1[f][5]=(short)f2bf(v1.y);
        a1[f][6]=(short)f2bf(v1.z); a1[f][7]=(short)f2bf(v1.w);
    }
    // layer1 -> LDS (bf16, A-ready layout)
    #pragma unroll
    for (int t = 0; t < 4; t++) {
        f32x4 c = {0.f, 0.f, 0.f, 0.f};
        #pragma unroll
        for (int f = 0; f < NF; f++)
            c = __builtin_amdgcn_mfma_f32_16x16x32_bf16(a1[f], w0f[t][f], c, 0, 0, 0);
        #pragma unroll
        for (int rg = 0; rg < 4; rg++) {
            int row = quad * 4 + rg;
            T[row * 72 + t * 16 + mn] = f2bf(fmaxf(c[rg] + b0v[t], 0.f));
        }
    }
    __syncthreads();
    // A2 frags from LDS
    bf8 a2[2];
    #pragma unroll
    for (int f = 0; f < 2; f++)
        a2[f] = *(const bf8*)&T[mn * 72 + f * 32 + quad * 8];
    // layer2 + epilogue: f32 direct store, bf16 back to LDS
    #pragma unroll
    for (int t = 0; t < 4; t++) {
        f32x4 c = {0.f, 0.f, 0.f, 0.f};
        c = __builtin_amdgcn_mfma_f32_16x16x32_bf16(a2[0], w1f[t][0], c, 0, 0, 0);
        c = __builtin_amdgcn_mfma_f32_16x16x32_bf16(a2[1], w1f[t][1], c, 0, 0, 0);
        #pragma unroll
        for (int rg = 0; rg < 4; rg++) {
            int row = quad * 4 + rg;
            int rowg = ebase + row;
            int rowc = (rowg < nrows) ? rowg : (nrows - 1);
            float v = c[rg] + b1v[t];
            if (RELU_RES) {
                float hv = hprev[(size_t)rowc * HID + t * 16 + mn];
                v = fmaxf(v + hv, 0.f);
            }
            if (rowg < nrows) out[(size_t)rowg * HID + t * 16 + mn] = v;
            T[row * 72 + t * 16 + mn] = f2bf(v);
        }
    }
    if (out_bf) {
        __syncthreads();
        int half = lane >> 5, c32 = lane & 31;
        #pragma unroll
        for (int rr = 0; rr < 8; rr++) {
            int row = rr * 2 + half;
            int pos = ebase + row;
            if (pos < nrows) {
                uint32 lo = T[row * 72 + c32 * 2];
                uint32 hi = T[row * 72 + c32 * 2 + 1];
                out_bf[(size_t)pos * 32 + c32] = lo | (hi << 16);
            }
        }
    }
}

// ---------------- edge MLP2 via MFMA (verified R8) ----------------

__global__ __launch_bounds__(256, 4) void k_edge_mlp_mfma(
    const float* __restrict__ eattr, const int* __restrict__ newpos,
    uint32* __restrict__ e_sorted,
    const float* __restrict__ w0, const float* __restrict__ b0,
    const float* __restrict__ w1, const float* __restrict__ b1)
{
    __shared__ ushort tile[4][16 * 72];  // per-wave 16 rows x 64 bf16 (+8 pad)
    const int wave = threadIdx.x >> 6, lane = threadIdx.x & 63;
    const int quad = lane >> 4, mn = lane & 15;
    ushort* T = &tile[wave][0];

    bf8 w0f[4];  // layer1 B-frags (K=16 zero-padded to 32)
    #pragma unroll
    for (int t = 0; t < 4; t++) {
        #pragma unroll
        for (int j = 0; j < 8; j++) {
            int k = quad * 8 + j;
            float v = (k < INE) ? w0[k * HID + t * 16 + mn] : 0.f;
            w0f[t][j] = (short)f2bf(v);
        }
    }
    bf8 w1f[4][2];
    #pragma unroll
    for (int t = 0; t < 4; t++)
        #pragma unroll
        for (int f = 0; f < 2; f++)
            #pragma unroll
            for (int j = 0; j < 8; j++) {
                int k = f * 32 + quad * 8 + j;
                w1f[t][f][j] = (short)f2bf(w1[k * HID + t * 16 + mn]);
            }
    float b0v[4], b1v[4];
    #pragma unroll
    for (int t = 0; t < 4; t++) { b0v[t] = b0[t*16+mn]; b1v[t] = b1[t*16+mn]; }

    const int nChunks = N_EDGES / 64;  // 15625 (exact)
    for (int chunk = blockIdx.x; chunk < nChunks; chunk += gridDim.x) {
        const int ebase = chunk * 64 + wave * 16;
        bf8 a1 = {};
        if (quad < 2) {
            const float4* pr = (const float4*)(eattr + (size_t)(ebase + mn) * INE + quad * 8);
            float4 v0 = pr[0], v1 = pr[1];
            a1[0]=(short)f2bf(v0.x); a1[1]=(short)f2bf(v0.y);
            a1[2]=(short)f2bf(v0.z); a1[3]=(short)f2bf(v0.w);
            a1[4]=(short)f2bf(v1.x); a1[5]=(short)f2bf(v1.y);
            a1[6]=(short)f2bf(v1.z); a1[7]=(short)f2bf(v1.w);
        }
        #pragma unroll
        for (int t = 0; t < 4; t++) {
            f32x4 c = {0.f, 0.f, 0.f, 0.f};
            c = __builtin_amdgcn_mfma_f32_16x16x32_bf16(a1, w0f[t], c, 0, 0, 0);
            #pragma unroll
            for (int rg = 0; rg < 4; rg++) {
                int row = quad * 4 + rg;
                T[row * 72 + t * 16 + mn] = f2bf(fmaxf(c[rg] + b0v[t], 0.f));
            }
        }
        __syncthreads();
        bf8 a2[2];
        #pragma unroll
        for (int f = 0; f < 2; f++)
            a2[f] = *(const bf8*)&T[mn * 72 + f * 32 + quad * 8];
        #pragma unroll
        for (int t = 0; t < 4; t++) {
            f32x4 c = {0.f, 0.f, 0.f, 0.f};
            c = __builtin_amdgcn_mfma_f32_16x16x32_bf16(a2[0], w1f[t][0], c, 0, 0, 0);
            c = __builtin_amdgcn_mfma_f32_16x16x32_bf16(a2[1], w1f[t][1], c, 0, 0, 0);
            #pragma unroll
            for (int rg = 0; rg < 4; rg++) {
                int row = quad * 4 + rg;
                T[row * 72 + t * 16 + mn] = f2bf(c[rg] + b1v[t]);
            }
        }
        __syncthreads();
        int half = lane >> 5, c32 = lane & 31;
        #pragma unroll
        for (int rr = 0; rr < 8; rr++) {
            int row = rr * 2 + half;
            int drow = newpos[ebase + row];
            uint32 lo = T[row * 72 + c32 * 2];
            uint32 hi = T[row * 72 + c32 * 2 + 1];
            e_sorted[(size_t)drow * 32 + c32] = lo | (hi << 16);
        }
        __syncthreads();
    }
}

// ------- GINE aggregation: z = sum relu(h[src]+e) + 1.1*h -------

__global__ __launch_bounds__(256, 4) void k_agg(
    const float* __restrict__ h, const uint32* __restrict__ h_bf,
    const uint32* __restrict__ e_sorted,
    const int* __restrict__ rowptr, const int* __restrict__ perm_src,
    float* __restrict__ z)
{
    int node = blockIdx.x * 4 + (threadIdx.x >> 6);
    if (node >= N_NODES) return;
    int lane = threadIdx.x & 63;
    int half = lane >> 5, c = lane & 31;   // this lane covers channels 2c, 2c+1
    int r0 = rowptr[node], r1 = rowptr[node + 1];
    const float2 hn = *(const float2*)&h[(size_t)node * HID + 2*c];  // early issue
    float accx = 0.f, accy = 0.f;
    #pragma unroll 1
    for (int base = r0; base < r1; base += 16) {
        int idxs[8]; int sidx[8];
        #pragma unroll
        for (int j = 0; j < 8; j++) {
            int idx = base + 2*j + half;
            idxs[j] = idx;
            int idxc = (idx < r1) ? idx : (r1 - 1);
            sidx[j] = perm_src[idxc];
        }
        uint32 hv[8], ev[8];
        #pragma unroll
        for (int j = 0; j < 8; j++) {
            int idxc = (idxs[j] < r1) ? idxs[j] : (r1 - 1);
            hv[j] = h_bf[(size_t)sidx[j] * 32 + c];
            ev[j] = e_sorted[(size_t)idxc * 32 + c];
        }
        #pragma unroll
        for (int j = 0; j < 8; j++) {
            float mx = fmaxf(bf_lo(hv[j]) + bf_lo(ev[j]), 0.f);
            float my = fmaxf(bf_hi(hv[j]) + bf_hi(ev[j]), 0.f);
            if (idxs[j] < r1) { accx += mx; accy += my; }
        }
    }
    accx += __shfl_xor(accx, 32);
    accy += __shfl_xor(accy, 32);
    if (half == 0) {
        float2 res;
        res.x = fmaf(1.1f, hn.x, accx);
        res.y = fmaf(1.1f, hn.y, accy);
        *(float2*)&z[(size_t)node * HID + 2*c] = res;
    }
}

// ---------------- global add pool (batch is sorted) ----------------

__global__ __launch_bounds__(256) void k_pool(
    const float* __restrict__ h, const int* __restrict__ batch, float* __restrict__ out)
{
    int g = blockIdx.x;
    int lane = threadIdx.x & 63, wave = threadIdx.x >> 6;
    int lo = 0, hi = N_NODES;
    while (lo < hi) { int mid = (lo + hi) >> 1; if (batch[mid] < g) lo = mid + 1; else hi = mid; }
    int start = lo;
    hi = N_NODES;
    while (lo < hi) { int mid = (lo + hi) >> 1; if (batch[mid] < g + 1) lo = mid + 1; else hi = mid; }
    int end = lo;
    float acc = 0.f;
    for (int n = start + wave; n < end; n += 4)
        acc += h[(size_t)n*HID + lane];
    __shared__ float sh[4][64];
    sh[wave][lane] = acc;
    __syncthreads();
    if (wave == 0)
        out[(size_t)g*HID + lane] = sh[0][lane] + sh[1][lane] + sh[2][lane] + sh[3][lane];
}

// ---------------- launch ----------------

extern "C" void kernel_launch(void* const* d_in, const int* in_sizes, int n_in,
                              void* d_out, int out_size, void* d_ws, size_t ws_size,
                              hipStream_t stream) {
    const float* x     = (const float*)d_in[0];
    const int*   eidx  = (const int*)  d_in[1];
    const float* eattr = (const float*)d_in[2];
    const int*   batch = (const int*)  d_in[3];
    const float* wn0 = (const float*)d_in[4];  const float* bn0 = (const float*)d_in[5];
    const float* wn1 = (const float*)d_in[6];  const float* bn1 = (const float*)d_in[7];
    const float* we0 = (const float*)d_in[8];  const float* be0 = (const float*)d_in[9];
    const float* we1 = (const float*)d_in[10]; const float* be1 = (const float*)d_in[11];
    const float* cw0 = (const float*)d_in[12]; const float* cb0 = (const float*)d_in[13];
    const float* cw1 = (const float*)d_in[14]; const float* cb1 = (const float*)d_in[15];
    const float* lw0 = (const float*)d_in[16]; const float* lb0 = (const float*)d_in[17];
    const float* lw1 = (const float*)d_in[18]; const float* lb1 = (const float*)d_in[19];
    const int* src = eidx;
    const int* dst = eidx + N_EDGES;

    // workspace layout (~201 MB)
    char* ws = (char*)d_ws;
    size_t off = 0;
    auto alloc = [&](size_t bytes) -> void* {
        void* p = ws + off;
        off = (off + bytes + 255) & ~(size_t)255;
        return p;
    };
    int*   counts   = (int*)  alloc((size_t)N_NODES * 4);
    int*   rowptr   = (int*)  alloc((size_t)(N_NODES + 1) * 4);
    int*   cursor   = (int*)  alloc((size_t)N_NODES * 4);
    int*   bsums    = (int*)  alloc(128 * 4);
    int*   perm_src = (int*)  alloc((size_t)N_EDGES * 4);
    int*   newpos   = (int*)  alloc((size_t)N_EDGES * 4);
    float* h        = (float*)alloc((size_t)N_NODES * HID * 4);
    float* zbuf     = (float*)alloc((size_t)N_NODES * HID * 4);
    uint32* h_bf    = (uint32*)alloc((size_t)N_NODES * 32 * 4);
    uint32* e_sorted = (uint32*)alloc((size_t)N_EDGES * HID * 2);
    if (off > ws_size) {
        k_diag<<<1, 64, 0, stream>>>((float*)d_out, 1.0e9f);
        return;
    }

    const int NB = (N_NODES + 1023) / 1024;  // 98

    hipMemsetAsync(counts, 0, (size_t)N_NODES * 4, stream);
    k_hist<<<(N_EDGES + 255) / 256, 256, 0, stream>>>(dst, counts);
    k_scan1<<<NB, 256, 0, stream>>>(counts, bsums);
    k_scan2<<<1, 128, 0, stream>>>(bsums, NB);
    k_scan3<<<NB, 256, 0, stream>>>(counts, bsums, rowptr, cursor);
    k_fill<<<(N_EDGES + 255) / 256, 256, 0, stream>>>(src, dst, cursor, perm_src, newpos);

    const int MGRID = (N_NODES + 63) / 64;  // 1563

    // node init MLP: x -> h (+ bf16 copy); wn0 natural [32][64]
    k_mlp_mfma<INN, false><<<MGRID, 256, 0, stream>>>(x, nullptr, h, wn0, bn0, wn1, bn1,
                                                      h_bf, N_NODES);

    // edge MLP via MFMA -> e_sorted (dst-sorted order, bf16)
    k_edge_mlp_mfma<<<1024, 256, 0, stream>>>(eattr, newpos, e_sorted,
                                              we0, be0, we1, be1);

    const int AGRID = (N_NODES + 3) / 4;  // 25000
    for (int l = 0; l < 3; l++) {
        k_agg<<<AGRID, 256, 0, stream>>>(h, h_bf, e_sorted, rowptr, perm_src, zbuf);
        k_mlp_mfma<HID, true><<<MGRID, 256, 0, stream>>>(zbuf, h, h,
                                                         cw0 + l * 4096, cb0 + l * 64,
                                                         cw1 + l * 4096, cb1 + l * 64,
                                                         h_bf, N_NODES);
    }
    // final GINE conv (no residual/relu, no bf copy needed)
    k_agg<<<AGRID, 256, 0, stream>>>(h, h_bf, e_sorted, rowptr, perm_src, zbuf);
    k_mlp_mfma<HID, false><<<MGRID, 256, 0, stream>>>(zbuf, nullptr, h,
                                                      lw0, lb0, lw1, lb1, nullptr, N_NODES);

    // global add pool
    k_pool<<<N_GRAPHS, 256, 0, stream>>>(h, batch, (float*)d_out);
}

// Round 10
// 575.895 us; speedup vs baseline: 1.9342x; 1.0553x over previous
//
#include <hip/hip_runtime.h>
#include <hip/hip_bf16.h>
#include <stdint.h>

#define N_NODES 100000
#define N_EDGES 1000000
#define N_GRAPHS 512
#define HID 64
#define INN 32
#define INE 16
#define CPAD 32   // counters padded to 1 per 128 B line (atomic same-line serialization fix)

typedef unsigned int uint32;
typedef unsigned short ushort16;
typedef __attribute__((ext_vector_type(8))) short bf8;
typedef __attribute__((ext_vector_type(4))) float f32x4;

__device__ __forceinline__ ushort16 f2bf(float f) {
    uint32 u = __float_as_uint(f);
    uint32 r = (u + 0x7fffu + ((u >> 16) & 1u)) >> 16;  // RNE
    return (ushort16)r;
}
__device__ __forceinline__ uint32 pack_bf2(float lo, float hi) {
    return (uint32)f2bf(lo) | ((uint32)f2bf(hi) << 16);
}
__device__ __forceinline__ float bf_lo(uint32 v) { return __uint_as_float(v << 16); }
__device__ __forceinline__ float bf_hi(uint32 v) { return __uint_as_float(v & 0xffff0000u); }

// ---------------- diag ----------------

__global__ void k_diag(float* out, float val) { out[threadIdx.x] = val; }

// ---------------- CSR build (padded counters) ----------------

__global__ void k_hist(const int* __restrict__ dst, int* __restrict__ counts) {
    int e = blockIdx.x * 256 + threadIdx.x;
    if (e < N_EDGES) atomicAdd(&counts[(size_t)dst[e] * CPAD], 1);
}

__global__ void k_scan1(const int* __restrict__ counts, int* __restrict__ bsums) {
    __shared__ int sdata[256];
    int b = blockIdx.x;
    int s = 0;
    for (int j = threadIdx.x; j < 1024; j += 256) {
        int i = b * 1024 + j;
        s += (i < N_NODES) ? counts[(size_t)i * CPAD] : 0;
    }
    sdata[threadIdx.x] = s; __syncthreads();
    for (int off = 128; off > 0; off >>= 1) {
        if (threadIdx.x < off) sdata[threadIdx.x] += sdata[threadIdx.x + off];
        __syncthreads();
    }
    if (threadIdx.x == 0) bsums[b] = sdata[0];
}

__global__ void k_scan2(int* __restrict__ bsums, int nb) {
    __shared__ int sh[128];
    int v = (threadIdx.x < nb) ? bsums[threadIdx.x] : 0;
    sh[threadIdx.x] = v; __syncthreads();
    for (int off = 1; off < 128; off <<= 1) {
        int t = (threadIdx.x >= off) ? sh[threadIdx.x - off] : 0;
        __syncthreads();
        sh[threadIdx.x] += t;
        __syncthreads();
    }
    if (threadIdx.x < nb) bsums[threadIdx.x] = sh[threadIdx.x] - v;  // exclusive
}

// in-place: reads counts[i*CPAD], writes cursor (same array) + rowptr
__global__ void k_scan3(int* __restrict__ counts_cursor, const int* __restrict__ bsums,
                        int* __restrict__ rowptr) {
    __shared__ int sh[256];
    int b = blockIdx.x;
    int base = b * 1024;
    int v[4]; int s = 0;
    #pragma unroll
    for (int j = 0; j < 4; j++) {
        int i = base + threadIdx.x * 4 + j;
        v[j] = (i < N_NODES) ? counts_cursor[(size_t)i * CPAD] : 0;
        s += v[j];
    }
    sh[threadIdx.x] = s; __syncthreads();
    for (int off = 1; off < 256; off <<= 1) {
        int t = (threadIdx.x >= off) ? sh[threadIdx.x - off] : 0;
        __syncthreads();
        sh[threadIdx.x] += t;
        __syncthreads();
    }
    int excl = sh[threadIdx.x] - s + bsums[b];
    #pragma unroll
    for (int j = 0; j < 4; j++) {
        int i = base + threadIdx.x * 4 + j;
        if (i < N_NODES) {
            rowptr[i] = excl;
            counts_cursor[(size_t)i * CPAD] = excl;  // becomes cursor
            excl += v[j];
        }
    }
    if (b == gridDim.x - 1 && threadIdx.x == 255) rowptr[N_NODES] = excl;
}

// newpos[e] = slot of edge e in the dst-sorted order (inverse permutation)
__global__ void k_fill(const int* __restrict__ src, const int* __restrict__ dst,
                       int* __restrict__ cursor, int* __restrict__ perm_src,
                       int* __restrict__ newpos) {
    int e = blockIdx.x * 256 + threadIdx.x;
    if (e < N_EDGES) {
        int d = dst[e];
        int p = atomicAdd(&cursor[(size_t)d * CPAD], 1);
        perm_src[p] = src[e];
        newpos[e] = p;
    }
}

// ---------------- node-side MLP2 via MFMA ----------------
// BF_IN: input rows are packed bf16 (32 uints/row) -> direct short8 A-frag loads.
// Otherwise f32 rows (K0 floats). Fragment layouts verified R8/R9.

template<int K0, bool RELU_RES, bool BF_IN>
__global__ __launch_bounds__(256, 3) void k_mlp_mfma(
    const void* __restrict__ in, const float* __restrict__ hprev, float* __restrict__ out,
    const float* __restrict__ w0, const float* __restrict__ b0,
    const float* __restrict__ w1, const float* __restrict__ b1,
    uint32* __restrict__ out_bf, int nrows)
{
    constexpr int NF = K0 / 32;  // K-frags for layer 1
    __shared__ ushort tile[4][16 * 72];
    const int wave = threadIdx.x >> 6, lane = threadIdx.x & 63;
    const int quad = lane >> 4, mn = lane & 15;
    ushort* T = &tile[wave][0];

    // ---- weight fragments: B[k][n=t*16+mn], k = f*32 + quad*8 + j ----
    bf8 w0f[4][NF];
    #pragma unroll
    for (int t = 0; t < 4; t++)
        #pragma unroll
        for (int f = 0; f < NF; f++)
            #pragma unroll
            for (int j = 0; j < 8; j++) {
                int k = f * 32 + quad * 8 + j;
                w0f[t][f][j] = (short)f2bf(w0[k * HID + t * 16 + mn]);
            }
    bf8 w1f[4][2];
    #pragma unroll
    for (int t = 0; t < 4; t++)
        #pragma unroll
        for (int f = 0; f < 2; f++)
            #pragma unroll
            for (int j = 0; j < 8; j++) {
                int k = f * 32 + quad * 8 + j;
                w1f[t][f][j] = (short)f2bf(w1[k * HID + t * 16 + mn]);
            }
    float b0v[4], b1v[4];
    #pragma unroll
    for (int t = 0; t < 4; t++) { b0v[t] = b0[t*16+mn]; b1v[t] = b1[t*16+mn]; }

    const int ebase = blockIdx.x * 64 + wave * 16;  // this wave's 16 rows
    int rowA = ebase + mn; if (rowA > nrows - 1) rowA = nrows - 1;
    bf8 a1[NF];
    if (BF_IN) {
        const ushort* row = (const ushort*)in + (size_t)rowA * HID;
        #pragma unroll
        for (int f = 0; f < NF; f++)
            a1[f] = *(const bf8*)(row + f * 32 + quad * 8);
    } else {
        const float* inf = (const float*)in;
        #pragma unroll
        for (int f = 0; f < NF; f++) {
            const float4* pr = (const float4*)(inf + (size_t)rowA * K0 + f * 32 + quad * 8);
            float4 v0 = pr[0], v1 = pr[1];
            a1[f][0]=(short)f2bf(v0.x); a1[f][1]=(short)f2bf(v0.y);
            a1[f][2]=(short)f2bf(v0.z); a1[f][3]=(short)f2bf(v0.w);
            a1[f][4]=(short)f2bf(v1.x); a1[f][5]=(short)f2bf(v1.y);
            a1[f][6]=(short)f2bf(v1.z); a1[f][7]=(short)f2bf(v1.w);
        }
    }
    // layer1 -> LDS (bf16, A-ready layout)
    #pragma unroll
    for (int t = 0; t < 4; t++) {
        f32x4 c = {0.f, 0.f, 0.f, 0.f};
        #pragma unroll
        for (int f = 0; f < NF; f++)
            c = __builtin_amdgcn_mfma_f32_16x16x32_bf16(a1[f], w0f[t][f], c, 0, 0, 0);
        #pragma unroll
        for (int rg = 0; rg < 4; rg++) {
            int row = quad * 4 + rg;
            T[row * 72 + t * 16 + mn] = f2bf(fmaxf(c[rg] + b0v[t], 0.f));
        }
    }
    __syncthreads();
    bf8 a2[2];
    #pragma unroll
    for (int f = 0; f < 2; f++)
        a2[f] = *(const bf8*)&T[mn * 72 + f * 32 + quad * 8];
    // layer2 + epilogue: f32 direct store, bf16 back to LDS
    #pragma unroll
    for (int t = 0; t < 4; t++) {
        f32x4 c = {0.f, 0.f, 0.f, 0.f};
        c = __builtin_amdgcn_mfma_f32_16x16x32_bf16(a2[0], w1f[t][0], c, 0, 0, 0);
        c = __builtin_amdgcn_mfma_f32_16x16x32_bf16(a2[1], w1f[t][1], c, 0, 0, 0);
        #pragma unroll
        for (int rg = 0; rg < 4; rg++) {
            int row = quad * 4 + rg;
            int rowg = ebase + row;
            int rowc = (rowg < nrows) ? rowg : (nrows - 1);
            float v = c[rg] + b1v[t];
            if (RELU_RES) {
                float hv = hprev[(size_t)rowc * HID + t * 16 + mn];
                v = fmaxf(v + hv, 0.f);
            }
            if (rowg < nrows) out[(size_t)rowg * HID + t * 16 + mn] = v;
            T[row * 72 + t * 16 + mn] = f2bf(v);
        }
    }
    if (out_bf) {
        __syncthreads();
        int half = lane >> 5, c32 = lane & 31;
        #pragma unroll
        for (int rr = 0; rr < 8; rr++) {
            int row = rr * 2 + half;
            int pos = ebase + row;
            if (pos < nrows) {
                uint32 lo = T[row * 72 + c32 * 2];
                uint32 hi = T[row * 72 + c32 * 2 + 1];
                out_bf[(size_t)pos * 32 + c32] = lo | (hi << 16);
            }
        }
    }
}

// ---------------- edge MLP2 via MFMA (verified R8) ----------------

__global__ __launch_bounds__(256, 4) void k_edge_mlp_mfma(
    const float* __restrict__ eattr, const int* __restrict__ newpos,
    uint32* __restrict__ e_sorted,
    const float* __restrict__ w0, const float* __restrict__ b0,
    const float* __restrict__ w1, const float* __restrict__ b1)
{
    __shared__ ushort tile[4][16 * 72];  // per-wave 16 rows x 64 bf16 (+8 pad)
    const int wave = threadIdx.x >> 6, lane = threadIdx.x & 63;
    const int quad = lane >> 4, mn = lane & 15;
    ushort* T = &tile[wave][0];

    bf8 w0f[4];  // layer1 B-frags (K=16 zero-padded to 32)
    #pragma unroll
    for (int t = 0; t < 4; t++) {
        #pragma unroll
        for (int j = 0; j < 8; j++) {
            int k = quad * 8 + j;
            float v = (k < INE) ? w0[k * HID + t * 16 + mn] : 0.f;
            w0f[t][j] = (short)f2bf(v);
        }
    }
    bf8 w1f[4][2];
    #pragma unroll
    for (int t = 0; t < 4; t++)
        #pragma unroll
        for (int f = 0; f < 2; f++)
            #pragma unroll
            for (int j = 0; j < 8; j++) {
                int k = f * 32 + quad * 8 + j;
                w1f[t][f][j] = (short)f2bf(w1[k * HID + t * 16 + mn]);
            }
    float b0v[4], b1v[4];
    #pragma unroll
    for (int t = 0; t < 4; t++) { b0v[t] = b0[t*16+mn]; b1v[t] = b1[t*16+mn]; }

    const int nChunks = N_EDGES / 64;  // 15625 (exact)
    for (int chunk = blockIdx.x; chunk < nChunks; chunk += gridDim.x) {
        const int ebase = chunk * 64 + wave * 16;
        bf8 a1 = {};
        if (quad < 2) {
            const float4* pr = (const float4*)(eattr + (size_t)(ebase + mn) * INE + quad * 8);
            float4 v0 = pr[0], v1 = pr[1];
            a1[0]=(short)f2bf(v0.x); a1[1]=(short)f2bf(v0.y);
            a1[2]=(short)f2bf(v0.z); a1[3]=(short)f2bf(v0.w);
            a1[4]=(short)f2bf(v1.x); a1[5]=(short)f2bf(v1.y);
            a1[6]=(short)f2bf(v1.z); a1[7]=(short)f2bf(v1.w);
        }
        #pragma unroll
        for (int t = 0; t < 4; t++) {
            f32x4 c = {0.f, 0.f, 0.f, 0.f};
            c = __builtin_amdgcn_mfma_f32_16x16x32_bf16(a1, w0f[t], c, 0, 0, 0);
            #pragma unroll
            for (int rg = 0; rg < 4; rg++) {
                int row = quad * 4 + rg;
                T[row * 72 + t * 16 + mn] = f2bf(fmaxf(c[rg] + b0v[t], 0.f));
            }
        }
        __syncthreads();
        bf8 a2[2];
        #pragma unroll
        for (int f = 0; f < 2; f++)
            a2[f] = *(const bf8*)&T[mn * 72 + f * 32 + quad * 8];
        #pragma unroll
        for (int t = 0; t < 4; t++) {
            f32x4 c = {0.f, 0.f, 0.f, 0.f};
            c = __builtin_amdgcn_mfma_f32_16x16x32_bf16(a2[0], w1f[t][0], c, 0, 0, 0);
            c = __builtin_amdgcn_mfma_f32_16x16x32_bf16(a2[1], w1f[t][1], c, 0, 0, 0);
            #pragma unroll
            for (int rg = 0; rg < 4; rg++) {
                int row = quad * 4 + rg;
                T[row * 72 + t * 16 + mn] = f2bf(c[rg] + b1v[t]);
            }
        }
        __syncthreads();
        int half = lane >> 5, c32 = lane & 31;
        #pragma unroll
        for (int rr = 0; rr < 8; rr++) {
            int row = rr * 2 + half;
            int drow = newpos[ebase + row];
            uint32 lo = T[row * 72 + c32 * 2];
            uint32 hi = T[row * 72 + c32 * 2 + 1];
            e_sorted[(size_t)drow * 32 + c32] = lo | (hi << 16);
        }
        __syncthreads();
    }
}

// ------- GINE aggregation: z = sum relu(h[src]+e) + 1.1*h -> packed bf16 z -------

__global__ __launch_bounds__(256, 4) void k_agg(
    const float* __restrict__ h, const uint32* __restrict__ h_bf,
    const uint32* __restrict__ e_sorted,
    const int* __restrict__ rowptr, const int* __restrict__ perm_src,
    uint32* __restrict__ z_bf)
{
    int node = blockIdx.x * 4 + (threadIdx.x >> 6);
    if (node >= N_NODES) return;
    int lane = threadIdx.x & 63;
    int half = lane >> 5, c = lane & 31;   // this lane covers channels 2c, 2c+1
    int r0 = rowptr[node], r1 = rowptr[node + 1];
    const float2 hn = *(const float2*)&h[(size_t)node * HID + 2*c];  // early issue
    float accx = 0.f, accy = 0.f;
    #pragma unroll 1
    for (int base = r0; base < r1; base += 16) {
        int idxs[8]; int sidx[8];
        #pragma unroll
        for (int j = 0; j < 8; j++) {
            int idx = base + 2*j + half;
            idxs[j] = idx;
            int idxc = (idx < r1) ? idx : (r1 - 1);
            sidx[j] = perm_src[idxc];
        }
        uint32 hv[8], ev[8];
        #pragma unroll
        for (int j = 0; j < 8; j++) {
            int idxc = (idxs[j] < r1) ? idxs[j] : (r1 - 1);
            hv[j] = h_bf[(size_t)sidx[j] * 32 + c];
            ev[j] = e_sorted[(size_t)idxc * 32 + c];
        }
        #pragma unroll
        for (int j = 0; j < 8; j++) {
            float mx = fmaxf(bf_lo(hv[j]) + bf_lo(ev[j]), 0.f);
            float my = fmaxf(bf_hi(hv[j]) + bf_hi(ev[j]), 0.f);
            if (idxs[j] < r1) { accx += mx; accy += my; }
        }
    }
    accx += __shfl_xor(accx, 32);
    accy += __shfl_xor(accy, 32);
    if (half == 0) {
        float rx = fmaf(1.1f, hn.x, accx);
        float ry = fmaf(1.1f, hn.y, accy);
        z_bf[(size_t)node * 32 + c] = pack_bf2(rx, ry);
    }
}

// ---------------- global add pool (batch is sorted) ----------------

__global__ __launch_bounds__(256) void k_pool(
    const float* __restrict__ h, const int* __restrict__ batch, float* __restrict__ out)
{
    int g = blockIdx.x;
    int lane = threadIdx.x & 63, wave = threadIdx.x >> 6;
    int lo = 0, hi = N_NODES;
    while (lo < hi) { int mid = (lo + hi) >> 1; if (batch[mid] < g) lo = mid + 1; else hi = mid; }
    int start = lo;
    hi = N_NODES;
    while (lo < hi) { int mid = (lo + hi) >> 1; if (batch[mid] < g + 1) lo = mid + 1; else hi = mid; }
    int end = lo;
    float acc = 0.f;
    for (int n = start + wave; n < end; n += 4)
        acc += h[(size_t)n*HID + lane];
    __shared__ float sh[4][64];
    sh[wave][lane] = acc;
    __syncthreads();
    if (wave == 0)
        out[(size_t)g*HID + lane] = sh[0][lane] + sh[1][lane] + sh[2][lane] + sh[3][lane];
}

// ---------------- launch ----------------

extern "C" void kernel_launch(void* const* d_in, const int* in_sizes, int n_in,
                              void* d_out, int out_size, void* d_ws, size_t ws_size,
                              hipStream_t stream) {
    const float* x     = (const float*)d_in[0];
    const int*   eidx  = (const int*)  d_in[1];
    const float* eattr = (const float*)d_in[2];
    const int*   batch = (const int*)  d_in[3];
    const float* wn0 = (const float*)d_in[4];  const float* bn0 = (const float*)d_in[5];
    const float* wn1 = (const float*)d_in[6];  const float* bn1 = (const float*)d_in[7];
    const float* we0 = (const float*)d_in[8];  const float* be0 = (const float*)d_in[9];
    const float* we1 = (const float*)d_in[10]; const float* be1 = (const float*)d_in[11];
    const float* cw0 = (const float*)d_in[12]; const float* cb0 = (const float*)d_in[13];
    const float* cw1 = (const float*)d_in[14]; const float* cb1 = (const float*)d_in[15];
    const float* lw0 = (const float*)d_in[16]; const float* lb0 = (const float*)d_in[17];
    const float* lw1 = (const float*)d_in[18]; const float* lb1 = (const float*)d_in[19];
    const int* src = eidx;
    const int* dst = eidx + N_EDGES;

    // workspace layout (~200 MB)
    char* ws = (char*)d_ws;
    size_t off = 0;
    auto alloc = [&](size_t bytes) -> void* {
        void* p = ws + off;
        off = (off + bytes + 255) & ~(size_t)255;
        return p;
    };
    int*   cc       = (int*)  alloc((size_t)N_NODES * CPAD * 4);  // counts, then cursor (aliased)
    int*   rowptr   = (int*)  alloc((size_t)(N_NODES + 1) * 4);
    int*   bsums    = (int*)  alloc(128 * 4);
    int*   perm_src = (int*)  alloc((size_t)N_EDGES * 4);
    int*   newpos   = (int*)  alloc((size_t)N_EDGES * 4);
    float* h        = (float*)alloc((size_t)N_NODES * HID * 4);
    uint32* z_bf    = (uint32*)alloc((size_t)N_NODES * 32 * 4);
    uint32* h_bf    = (uint32*)alloc((size_t)N_NODES * 32 * 4);
    uint32* e_sorted = (uint32*)alloc((size_t)N_EDGES * HID * 2);
    if (off > ws_size) {
        k_diag<<<1, 64, 0, stream>>>((float*)d_out, 1.0e9f);
        return;
    }

    const int NB = (N_NODES + 1023) / 1024;  // 98

    hipMemsetAsync(cc, 0, (size_t)N_NODES * CPAD * 4, stream);
    k_hist<<<(N_EDGES + 255) / 256, 256, 0, stream>>>(dst, cc);
    k_scan1<<<NB, 256, 0, stream>>>(cc, bsums);
    k_scan2<<<1, 128, 0, stream>>>(bsums, NB);
    k_scan3<<<NB, 256, 0, stream>>>(cc, bsums, rowptr);
    k_fill<<<(N_EDGES + 255) / 256, 256, 0, stream>>>(src, dst, cc, perm_src, newpos);

    const int MGRID = (N_NODES + 63) / 64;  // 1563

    // node init MLP: x (f32) -> h (+ bf16 copy)
    k_mlp_mfma<INN, false, false><<<MGRID, 256, 0, stream>>>(x, nullptr, h, wn0, bn0, wn1, bn1,
                                                             h_bf, N_NODES);

    // edge MLP via MFMA -> e_sorted (dst-sorted order, bf16)
    k_edge_mlp_mfma<<<1024, 256, 0, stream>>>(eattr, newpos, e_sorted,
                                              we0, be0, we1, be1);

    const int AGRID = (N_NODES + 3) / 4;  // 25000
    for (int l = 0; l < 3; l++) {
        k_agg<<<AGRID, 256, 0, stream>>>(h, h_bf, e_sorted, rowptr, perm_src, z_bf);
        k_mlp_mfma<HID, true, true><<<MGRID, 256, 0, stream>>>(z_bf, h, h,
                                                               cw0 + l * 4096, cb0 + l * 64,
                                                               cw1 + l * 4096, cb1 + l * 64,
                                                               h_bf, N_NODES);
    }
    // final GINE conv (no residual/relu, no bf copy needed)
    k_agg<<<AGRID, 256, 0, stream>>>(h, h_bf, e_sorted, rowptr, perm_src, z_bf);
    k_mlp_mfma<HID, false, true><<<MGRID, 256, 0, stream>>>(z_bf, nullptr, h,
                                                            lw0, lb0, lw1, lb1, nullptr, N_NODES);

    // global add pool
    k_pool<<<N_GRAPHS, 256, 0, stream>>>(h, batch, (float*)d_out);
}